// Round 1
// baseline (643.984 us; speedup 1.0000x reference)
//
#include <hip/hip_runtime.h>

#define N_NODES 100000
#define N_EDGES 1600000
#define NFEAT 256
#define NHID 128
#define NCLASS 40

// ---------------- CSR build ----------------

__global__ void k_hist(const int* __restrict__ dst, int* __restrict__ deg) {
  int e = blockIdx.x * 256 + threadIdx.x;
  if (e < N_EDGES) atomicAdd(&deg[dst[e]], 1);
}

__global__ void k_scan1(const int* __restrict__ deg, int* __restrict__ rowptr,
                        int* __restrict__ bsums) {
  __shared__ int s[256];
  int t = threadIdx.x;
  int i = blockIdx.x * 256 + t;
  int v = (i < N_NODES) ? deg[i] : 0;
  s[t] = v;
  __syncthreads();
  for (int off = 1; off < 256; off <<= 1) {
    int u = (t >= off) ? s[t - off] : 0;
    __syncthreads();
    s[t] += u;
    __syncthreads();
  }
  if (i < N_NODES) rowptr[i + 1] = s[t];
  if (t == 255) bsums[blockIdx.x] = s[255];
  if (i == 0) rowptr[0] = 0;
}

__global__ void k_scan2(int* __restrict__ bsums, int nb) {
  __shared__ int s[512];
  int t = threadIdx.x;
  int v = (t < nb) ? bsums[t] : 0;
  s[t] = v;
  __syncthreads();
  for (int off = 1; off < 512; off <<= 1) {
    int u = (t >= off) ? s[t - off] : 0;
    __syncthreads();
    s[t] += u;
    __syncthreads();
  }
  if (t < nb) bsums[t] = s[t] - v;  // exclusive
}

__global__ void k_scan3(int* __restrict__ rowptr, const int* __restrict__ bsums) {
  int i = blockIdx.x * 256 + threadIdx.x;
  if (i < N_NODES) rowptr[i + 1] += bsums[blockIdx.x];
}

__global__ void k_scatter(const int* __restrict__ src, const int* __restrict__ dst,
                          const float* __restrict__ w, const int* __restrict__ rowptr,
                          int* __restrict__ cursor, int* __restrict__ esrc,
                          float* __restrict__ ew) {
  int e = blockIdx.x * 256 + threadIdx.x;
  if (e < N_EDGES) {
    int d = dst[e];
    int pos = rowptr[d] + atomicAdd(&cursor[d], 1);
    esrc[pos] = src[e];
    ew[pos] = w[e];
  }
}

// ---------------- GEMM1: h1 = x @ W1  (f32, 64x128 tile) ----------------

__global__ __launch_bounds__(256) void k_gemm1(const float* __restrict__ x,
                                               const float* __restrict__ W1,
                                               float* __restrict__ h1) {
  __shared__ float As[32][68];   // [k][m], padded, 16B-aligned rows (68*4=272)
  __shared__ float Bs[32][128];  // [k][n]
  int tid = threadIdx.x;
  int row0 = blockIdx.x * 64;
  int ty = tid / 16, tx = tid % 16;  // thread -> rows ty*4..+4, cols tx*8..+8
  float c[4][8] = {};

  for (int kt = 0; kt < NFEAT; kt += 32) {
    // load x tile 64x32
    {
      int r = tid / 8;
      int c4 = (tid % 8) * 4;
      for (int rr = r; rr < 64; rr += 32) {
        int grow = row0 + rr;
        float4 v = make_float4(0.f, 0.f, 0.f, 0.f);
        if (grow < N_NODES) v = *(const float4*)&x[grow * NFEAT + kt + c4];
        As[c4 + 0][rr] = v.x;
        As[c4 + 1][rr] = v.y;
        As[c4 + 2][rr] = v.z;
        As[c4 + 3][rr] = v.w;
      }
    }
    // load W1 tile 32x128
    {
      int k = tid / 32;
      int n4 = (tid % 32) * 4;
      for (int kk = k; kk < 32; kk += 8) {
        *(float4*)&Bs[kk][n4] = *(const float4*)&W1[(kt + kk) * NHID + n4];
      }
    }
    __syncthreads();
#pragma unroll 8
    for (int k = 0; k < 32; k++) {
      float a[4], b[8];
      *(float4*)a = *(float4*)&As[k][ty * 4];
      *(float4*)b = *(float4*)&Bs[k][tx * 8];
      *(float4*)(b + 4) = *(float4*)&Bs[k][tx * 8 + 4];
#pragma unroll
      for (int i = 0; i < 4; i++)
#pragma unroll
        for (int j = 0; j < 8; j++) c[i][j] += a[i] * b[j];
    }
    __syncthreads();
  }
  for (int i = 0; i < 4; i++) {
    int grow = row0 + ty * 4 + i;
    if (grow < N_NODES) {
      *(float4*)&h1[grow * NHID + tx * 8] = *(float4*)&c[i][0];
      *(float4*)&h1[grow * NHID + tx * 8 + 4] = *(float4*)&c[i][4];
    }
  }
}

// ---------------- SpMM1 + bias + ReLU: one wave per node ----------------

__global__ __launch_bounds__(256) void k_spmm1(const float* __restrict__ h1,
                                               const int* __restrict__ rowptr,
                                               const int* __restrict__ esrc,
                                               const float* __restrict__ ew,
                                               const float* __restrict__ b1,
                                               float* __restrict__ hout) {
  int wave = (blockIdx.x * 256 + threadIdx.x) >> 6;
  int lane = threadIdx.x & 63;
  if (wave >= N_NODES) return;
  int beg = rowptr[wave], end = rowptr[wave + 1];
  float acc0 = 0.f, acc1 = 0.f;
  for (int j = beg; j < end; j++) {
    int s = esrc[j];
    float w = ew[j];
    acc0 += w * h1[s * NHID + lane];
    acc1 += w * h1[s * NHID + 64 + lane];
  }
  hout[wave * NHID + lane] = fmaxf(acc0 + b1[lane], 0.f);
  hout[wave * NHID + 64 + lane] = fmaxf(acc1 + b1[64 + lane], 0.f);
}

// ---------------- GEMM2: h2 = h @ W2  (128x40) ----------------

__global__ __launch_bounds__(256) void k_gemm2(const float* __restrict__ h,
                                               const float* __restrict__ W2,
                                               float* __restrict__ h2) {
  __shared__ float hs[32][132];   // padded: bank (4r+k)%32
  __shared__ float w2t[40][132];  // W2 transposed [c][k]
  int tid = threadIdx.x;
  int row0 = blockIdx.x * 32;
  for (int i = tid; i < NHID * NCLASS; i += 256) {
    int k = i / NCLASS, c = i % NCLASS;
    w2t[c][k] = W2[i];
  }
  for (int i = tid; i < 1024; i += 256) {  // 32*128/4 float4 loads
    int r = i >> 5;
    int c4 = (i & 31) << 2;
    *(float4*)&hs[r][c4] = *(const float4*)&h[(row0 + r) * NHID + c4];
  }
  __syncthreads();
  int r = tid >> 3;
  int c0 = (tid & 7) * 5;
  float acc[5] = {0, 0, 0, 0, 0};
  for (int k = 0; k < NHID; k += 4) {
    float4 a = *(float4*)&hs[r][k];
#pragma unroll
    for (int j = 0; j < 5; j++) {
      float4 b = *(float4*)&w2t[c0 + j][k];
      acc[j] += a.x * b.x + a.y * b.y + a.z * b.z + a.w * b.w;
    }
  }
#pragma unroll
  for (int j = 0; j < 5; j++) h2[(row0 + r) * NCLASS + c0 + j] = acc[j];
}

// ---------------- SpMM2 + bias: one wave per node (40 lanes active) ----------------

__global__ __launch_bounds__(256) void k_spmm2(const float* __restrict__ h2,
                                               const int* __restrict__ rowptr,
                                               const int* __restrict__ esrc,
                                               const float* __restrict__ ew,
                                               const float* __restrict__ b2,
                                               float* __restrict__ out) {
  int wave = (blockIdx.x * 256 + threadIdx.x) >> 6;
  int lane = threadIdx.x & 63;
  if (wave >= N_NODES) return;
  int beg = rowptr[wave], end = rowptr[wave + 1];
  if (lane < NCLASS) {
    float acc = 0.f;
    for (int j = beg; j < end; j++) {
      acc += ew[j] * h2[esrc[j] * NCLASS + lane];
    }
    out[wave * NCLASS + lane] = acc + b2[lane];
  }
}

extern "C" void kernel_launch(void* const* d_in, const int* in_sizes, int n_in,
                              void* d_out, int out_size, void* d_ws, size_t ws_size,
                              hipStream_t stream) {
  const float* x = (const float*)d_in[0];
  const int* src_in = (const int*)d_in[1];
  const int* dst_in = (const int*)d_in[2];
  const float* w_in = (const float*)d_in[3];
  const float* W1 = (const float*)d_in[4];
  const float* b1 = (const float*)d_in[5];
  const float* W2 = (const float*)d_in[6];
  const float* b2 = (const float*)d_in[7];
  float* out = (float*)d_out;

  // workspace layout (all 16B-aligned chunks)
  float* h1 = (float*)d_ws;                          // 12.8M f
  float* hbuf = h1 + (size_t)N_NODES * NHID;         // 12.8M f
  float* h2 = hbuf + (size_t)N_NODES * NHID;         // 4M f
  int* rowptr = (int*)(h2 + (size_t)N_NODES * NCLASS);  // N+1 (pad 100004)
  int* deg = rowptr + 100004;                        // N (doubles as cursor)
  int* bsums = deg + N_NODES;                        // 512
  int* esrc = bsums + 512;                           // E
  float* ew = (float*)(esrc + N_EDGES);              // E
  // total ~132 MB

  int nbN = (N_NODES + 255) / 256;  // 391
  int nbE = (N_EDGES + 255) / 256;  // 6250

  hipMemsetAsync(deg, 0, N_NODES * sizeof(int), stream);
  k_hist<<<nbE, 256, 0, stream>>>(dst_in, deg);
  k_scan1<<<nbN, 256, 0, stream>>>(deg, rowptr, bsums);
  k_scan2<<<1, 512, 0, stream>>>(bsums, nbN);
  k_scan3<<<nbN, 256, 0, stream>>>(rowptr, bsums);
  hipMemsetAsync(deg, 0, N_NODES * sizeof(int), stream);
  k_scatter<<<nbE, 256, 0, stream>>>(src_in, dst_in, w_in, rowptr, deg, esrc, ew);

  k_gemm1<<<(N_NODES + 63) / 64, 256, 0, stream>>>(x, W1, h1);
  k_spmm1<<<(N_NODES + 3) / 4, 256, 0, stream>>>(h1, rowptr, esrc, ew, b1, hbuf);
  k_gemm2<<<N_NODES / 32, 256, 0, stream>>>(hbuf, W2, h2);
  k_spmm2<<<(N_NODES + 3) / 4, 256, 0, stream>>>(h2, rowptr, esrc, ew, b2, out);
}

// Round 2
// 470.963 us; speedup vs baseline: 1.3674x; 1.3674x over previous
//
#include <hip/hip_runtime.h>

#define N_NODES 100000
#define N_EDGES 1600000
#define NFEAT 256
#define NHID 128
#define NCLASS 40

// ---------- bf16 helpers ----------
__device__ inline float blo(unsigned u) { return __uint_as_float(u << 16); }
__device__ inline float bhi(unsigned u) { return __uint_as_float(u & 0xffff0000u); }
__device__ inline unsigned pk2(float a, float b) {  // 2xf32 -> packed bf16 (RNE)
  unsigned x = __float_as_uint(a), y = __float_as_uint(b);
  unsigned lo = (x + 0x7FFFu + ((x >> 16) & 1u)) >> 16;
  unsigned hi = (y + 0x7FFFu + ((y >> 16) & 1u)) >> 16;
  return lo | (hi << 16);
}
__device__ inline unsigned short pk1(float a) {
  unsigned x = __float_as_uint(a);
  return (unsigned short)((x + 0x7FFFu + ((x >> 16) & 1u)) >> 16);
}

// ---------------- CSR build ----------------

__global__ void k_hist(const int* __restrict__ dst, int* __restrict__ deg) {
  int e = blockIdx.x * 256 + threadIdx.x;
  if (e < N_EDGES) atomicAdd(&deg[dst[e]], 1);
}

__global__ void k_scan1(const int* __restrict__ deg, int* __restrict__ rowptr,
                        int* __restrict__ bsums) {
  __shared__ int s[256];
  int t = threadIdx.x;
  int i = blockIdx.x * 256 + t;
  int v = (i < N_NODES) ? deg[i] : 0;
  s[t] = v;
  __syncthreads();
  for (int off = 1; off < 256; off <<= 1) {
    int u = (t >= off) ? s[t - off] : 0;
    __syncthreads();
    s[t] += u;
    __syncthreads();
  }
  if (i < N_NODES) rowptr[i + 1] = s[t];
  if (t == 255) bsums[blockIdx.x] = s[255];
  if (i == 0) rowptr[0] = 0;
}

__global__ void k_scan2(int* __restrict__ bsums, int nb) {
  __shared__ int s[512];
  int t = threadIdx.x;
  int v = (t < nb) ? bsums[t] : 0;
  s[t] = v;
  __syncthreads();
  for (int off = 1; off < 512; off <<= 1) {
    int u = (t >= off) ? s[t - off] : 0;
    __syncthreads();
    s[t] += u;
    __syncthreads();
  }
  if (t < nb) bsums[t] = s[t] - v;  // exclusive
}

__global__ void k_scan3(int* __restrict__ rowptr, const int* __restrict__ bsums) {
  int i = blockIdx.x * 256 + threadIdx.x;
  if (i < N_NODES) rowptr[i + 1] += bsums[blockIdx.x];
}

__global__ void k_scatter(const int* __restrict__ src, const int* __restrict__ dst,
                          const float* __restrict__ w, const int* __restrict__ rowptr,
                          int* __restrict__ cursor, int2* __restrict__ esw) {
  int e = blockIdx.x * 256 + threadIdx.x;
  if (e < N_EDGES) {
    int d = dst[e];
    int pos = rowptr[d] + atomicAdd(&cursor[d], 1);
    esw[pos] = make_int2(src[e], __float_as_int(w[e]));
  }
}

// ---------------- GEMM1: h1 = x @ W1  (f32 compute, bf16 out) ----------------

__global__ __launch_bounds__(256) void k_gemm1(const float* __restrict__ x,
                                               const float* __restrict__ W1,
                                               unsigned* __restrict__ h1u) {
  __shared__ float As[32][68];   // [k][m], padded
  __shared__ float Bs[32][128];  // [k][n]
  int tid = threadIdx.x;
  int row0 = blockIdx.x * 64;
  int ty = tid / 16, tx = tid % 16;  // rows ty*4..+4, cols tx*8..+8
  float c[4][8] = {};

  for (int kt = 0; kt < NFEAT; kt += 32) {
    {
      int r = tid / 8;
      int c4 = (tid % 8) * 4;
      for (int rr = r; rr < 64; rr += 32) {
        int grow = row0 + rr;
        float4 v = make_float4(0.f, 0.f, 0.f, 0.f);
        if (grow < N_NODES) v = *(const float4*)&x[(size_t)grow * NFEAT + kt + c4];
        As[c4 + 0][rr] = v.x;
        As[c4 + 1][rr] = v.y;
        As[c4 + 2][rr] = v.z;
        As[c4 + 3][rr] = v.w;
      }
    }
    {
      int k = tid / 32;
      int n4 = (tid % 32) * 4;
      for (int kk = k; kk < 32; kk += 8) {
        *(float4*)&Bs[kk][n4] = *(const float4*)&W1[(size_t)(kt + kk) * NHID + n4];
      }
    }
    __syncthreads();
#pragma unroll 8
    for (int k = 0; k < 32; k++) {
      float a[4], b[8];
      *(float4*)a = *(float4*)&As[k][ty * 4];
      *(float4*)b = *(float4*)&Bs[k][tx * 8];
      *(float4*)(b + 4) = *(float4*)&Bs[k][tx * 8 + 4];
#pragma unroll
      for (int i = 0; i < 4; i++)
#pragma unroll
        for (int j = 0; j < 8; j++) c[i][j] += a[i] * b[j];
    }
    __syncthreads();
  }
  for (int i = 0; i < 4; i++) {
    int grow = row0 + ty * 4 + i;
    if (grow < N_NODES) {
      uint4 o;
      o.x = pk2(c[i][0], c[i][1]);
      o.y = pk2(c[i][2], c[i][3]);
      o.z = pk2(c[i][4], c[i][5]);
      o.w = pk2(c[i][6], c[i][7]);
      *(uint4*)&h1u[(size_t)grow * 64 + tx * 4] = o;
    }
  }
}

// ---------------- SpMM1 + bias + ReLU: one wave per node, bf16 gather ----------------

__global__ __launch_bounds__(256) void k_spmm1(const unsigned* __restrict__ h1u,
                                               const int* __restrict__ rowptr,
                                               const int2* __restrict__ esw,
                                               const float* __restrict__ bias1,
                                               float* __restrict__ hout) {
  int node = (blockIdx.x * 256 + threadIdx.x) >> 6;
  int lane = threadIdx.x & 63;
  if (node >= N_NODES) return;
  int beg = rowptr[node], end = rowptr[node + 1];
  float a0 = 0.f, a1 = 0.f, c0 = 0.f, c1 = 0.f;
  int j = beg;
  for (; j + 1 < end; j += 2) {
    int2 e0 = esw[j];
    int2 e1 = esw[j + 1];
    unsigned u0 = h1u[(size_t)e0.x * 64 + lane];
    unsigned u1 = h1u[(size_t)e1.x * 64 + lane];
    float w0 = __int_as_float(e0.y), w1 = __int_as_float(e1.y);
    a0 = fmaf(w0, blo(u0), a0);
    a1 = fmaf(w0, bhi(u0), a1);
    c0 = fmaf(w1, blo(u1), c0);
    c1 = fmaf(w1, bhi(u1), c1);
  }
  if (j < end) {
    int2 e0 = esw[j];
    unsigned u0 = h1u[(size_t)e0.x * 64 + lane];
    float w0 = __int_as_float(e0.y);
    a0 = fmaf(w0, blo(u0), a0);
    a1 = fmaf(w0, bhi(u0), a1);
  }
  float r0 = a0 + c0 + bias1[2 * lane];
  float r1 = a1 + c1 + bias1[2 * lane + 1];
  float2 o = make_float2(fmaxf(r0, 0.f), fmaxf(r1, 0.f));
  *(float2*)&hout[(size_t)node * NHID + 2 * lane] = o;
}

// ---------------- GEMM2: h2 = h @ W2  (f32 in, bf16 out) ----------------

__global__ __launch_bounds__(256) void k_gemm2(const float* __restrict__ h,
                                               const float* __restrict__ W2,
                                               unsigned short* __restrict__ h2b) {
  __shared__ float hs[32][132];
  __shared__ float w2t[40][132];
  int tid = threadIdx.x;
  int row0 = blockIdx.x * 32;
  for (int i = tid; i < NHID * NCLASS; i += 256) {
    int k = i / NCLASS, c = i % NCLASS;
    w2t[c][k] = W2[i];
  }
  for (int i = tid; i < 1024; i += 256) {
    int r = i >> 5;
    int c4 = (i & 31) << 2;
    *(float4*)&hs[r][c4] = *(const float4*)&h[(size_t)(row0 + r) * NHID + c4];
  }
  __syncthreads();
  int r = tid >> 3;
  int c0 = (tid & 7) * 5;
  float acc[5] = {0, 0, 0, 0, 0};
  for (int k = 0; k < NHID; k += 4) {
    float4 a = *(float4*)&hs[r][k];
#pragma unroll
    for (int j = 0; j < 5; j++) {
      float4 b = *(float4*)&w2t[c0 + j][k];
      acc[j] += a.x * b.x + a.y * b.y + a.z * b.z + a.w * b.w;
    }
  }
#pragma unroll
  for (int j = 0; j < 5; j++) h2b[(size_t)(row0 + r) * NCLASS + c0 + j] = pk1(acc[j]);
}

// ---------------- SpMM2 + bias: wave per node, 3-way edge split, bf16 gather ----------------

__global__ __launch_bounds__(256) void k_spmm2(const unsigned* __restrict__ h2u,
                                               const int* __restrict__ rowptr,
                                               const int2* __restrict__ esw,
                                               const float* __restrict__ b2,
                                               float* __restrict__ out) {
  int node = (blockIdx.x * 256 + threadIdx.x) >> 6;
  int lane = threadIdx.x & 63;
  if (node >= N_NODES) return;
  int beg = rowptr[node], end = rowptr[node + 1];
  int g = lane / 20;       // 0..2 active, 3 = idle tail (lanes 60..63)
  int jj = lane - g * 20;  // 0..19
  float accA = 0.f, accB = 0.f;
  if (g < 3) {
    for (int e = beg + g; e < end; e += 3) {
      int2 p = esw[e];
      unsigned u = h2u[(size_t)p.x * 20 + jj];
      float w = __int_as_float(p.y);
      accA = fmaf(w, blo(u), accA);
      accB = fmaf(w, bhi(u), accB);
    }
  }
  // reduce across the 3 edge-groups: lanes jj, jj+20, jj+40
  float tA = accA + __shfl(accA, lane + 20) + __shfl(accA, lane + 40);
  float tB = accB + __shfl(accB, lane + 20) + __shfl(accB, lane + 40);
  if (lane < 20) {
    float2 o = make_float2(tA + b2[2 * lane], tB + b2[2 * lane + 1]);
    *(float2*)&out[(size_t)node * NCLASS + 2 * lane] = o;
  }
}

extern "C" void kernel_launch(void* const* d_in, const int* in_sizes, int n_in,
                              void* d_out, int out_size, void* d_ws, size_t ws_size,
                              hipStream_t stream) {
  const float* x = (const float*)d_in[0];
  const int* src_in = (const int*)d_in[1];
  const int* dst_in = (const int*)d_in[2];
  const float* w_in = (const float*)d_in[3];
  const float* W1 = (const float*)d_in[4];
  const float* b1 = (const float*)d_in[5];
  const float* W2 = (const float*)d_in[6];
  const float* b2 = (const float*)d_in[7];
  float* out = (float*)d_out;

  // workspace layout (16B-aligned chunks)
  unsigned short* h1b = (unsigned short*)d_ws;                    // 12.8M bf16 = 25.6 MB
  float* hbuf = (float*)(h1b + (size_t)N_NODES * NHID);           // 12.8M f32 = 51.2 MB
  unsigned short* h2b = (unsigned short*)(hbuf + (size_t)N_NODES * NHID);  // 4M bf16 = 8 MB
  int* rowptr = (int*)(h2b + (size_t)N_NODES * NCLASS);           // 100004 ints
  int* deg = rowptr + 100004;                                     // N (doubles as cursor)
  int* bsums = deg + N_NODES;                                     // 512
  int2* esw = (int2*)(bsums + 512);                               // E * 8B = 12.8 MB

  int nbN = (N_NODES + 255) / 256;  // 391
  int nbE = (N_EDGES + 255) / 256;  // 6250

  hipMemsetAsync(deg, 0, N_NODES * sizeof(int), stream);
  k_hist<<<nbE, 256, 0, stream>>>(dst_in, deg);
  k_scan1<<<nbN, 256, 0, stream>>>(deg, rowptr, bsums);
  k_scan2<<<1, 512, 0, stream>>>(bsums, nbN);
  k_scan3<<<nbN, 256, 0, stream>>>(rowptr, bsums);
  hipMemsetAsync(deg, 0, N_NODES * sizeof(int), stream);
  k_scatter<<<nbE, 256, 0, stream>>>(src_in, dst_in, w_in, rowptr, deg, esw);

  k_gemm1<<<(N_NODES + 63) / 64, 256, 0, stream>>>(x, W1, (unsigned*)h1b);
  k_spmm1<<<(N_NODES + 3) / 4, 256, 0, stream>>>((const unsigned*)h1b, rowptr, esw, b1, hbuf);
  k_gemm2<<<N_NODES / 32, 256, 0, stream>>>(hbuf, W2, h2b);
  k_spmm2<<<(N_NODES + 3) / 4, 256, 0, stream>>>((const unsigned*)h2b, rowptr, esw, b2, out);
}

// Round 3
// 378.944 us; speedup vs baseline: 1.6994x; 1.2428x over previous
//
#include <hip/hip_runtime.h>

#define N_NODES 100000
#define N_EDGES 1600000
#define NFEAT 256
#define NHID 128
#define NCLASS 40

using short8 = __attribute__((ext_vector_type(8))) short;
using f32x4 = __attribute__((ext_vector_type(4))) float;

// ---------- bf16 helpers ----------
__device__ inline float blo(unsigned u) { return __uint_as_float(u << 16); }
__device__ inline float bhi(unsigned u) { return __uint_as_float(u & 0xffff0000u); }
__device__ inline unsigned pk2(float a, float b) {  // 2xf32 -> packed bf16 (RNE)
  unsigned x = __float_as_uint(a), y = __float_as_uint(b);
  unsigned lo = (x + 0x7FFFu + ((x >> 16) & 1u)) >> 16;
  unsigned hi = (y + 0x7FFFu + ((y >> 16) & 1u)) >> 16;
  return lo | (hi << 16);
}
__device__ inline unsigned short pk1(float a) {
  unsigned x = __float_as_uint(a);
  return (unsigned short)((x + 0x7FFFu + ((x >> 16) & 1u)) >> 16);
}

// ---------------- CSR build ----------------

__global__ void k_hist(const int* __restrict__ dst, int* __restrict__ deg) {
  int e = blockIdx.x * 256 + threadIdx.x;
  if (e < N_EDGES) atomicAdd(&deg[dst[e]], 1);
}

__global__ void k_scan1(const int* __restrict__ deg, int* __restrict__ rowptr,
                        int* __restrict__ bsums) {
  __shared__ int s[256];
  int t = threadIdx.x;
  int i = blockIdx.x * 256 + t;
  int v = (i < N_NODES) ? deg[i] : 0;
  s[t] = v;
  __syncthreads();
  for (int off = 1; off < 256; off <<= 1) {
    int u = (t >= off) ? s[t - off] : 0;
    __syncthreads();
    s[t] += u;
    __syncthreads();
  }
  if (i < N_NODES) rowptr[i + 1] = s[t];
  if (t == 255) bsums[blockIdx.x] = s[255];
  if (i == 0) rowptr[0] = 0;
}

__global__ void k_scan2(int* __restrict__ bsums, int nb) {
  __shared__ int s[512];
  int t = threadIdx.x;
  int v = (t < nb) ? bsums[t] : 0;
  s[t] = v;
  __syncthreads();
  for (int off = 1; off < 512; off <<= 1) {
    int u = (t >= off) ? s[t - off] : 0;
    __syncthreads();
    s[t] += u;
    __syncthreads();
  }
  if (t < nb) bsums[t] = s[t] - v;  // exclusive
}

__global__ void k_scan3(int* __restrict__ rowptr, const int* __restrict__ bsums) {
  int i = blockIdx.x * 256 + threadIdx.x;
  if (i < N_NODES) rowptr[i + 1] += bsums[blockIdx.x];
}

__global__ void k_scatter(const int* __restrict__ src, const int* __restrict__ dst,
                          const float* __restrict__ w, const int* __restrict__ rowptr,
                          int* __restrict__ cursor, int2* __restrict__ esw) {
  int e = blockIdx.x * 256 + threadIdx.x;
  if (e < N_EDGES) {
    int d = dst[e];
    int pos = rowptr[d] + atomicAdd(&cursor[d], 1);
    esw[pos] = make_int2(src[e], __float_as_int(w[e]));
  }
}

// ---------------- W1 prep: bf16(W1^T) with XOR-swizzle, for linear LDS staging ----------------
// LDS target layout: Bt[c][k] (c=0..127 cols, k=0..255) at byte (c*512 + 2k) ^ ((c&7)<<4).
// Stored pre-swizzled in global so gemm1 copies linearly (rule: swizzle both sides or neither).

__global__ void k_prepw1(const float* __restrict__ W1, unsigned short* __restrict__ w1s) {
  int t = blockIdx.x * 256 + threadIdx.x;
  if (t < NFEAT * NHID) {
    int k = t >> 7, c = t & 127;
    int idx = (c * 256 + k) ^ ((c & 7) << 3);  // u16 index (byte XOR (c&7)<<4)
    w1s[idx] = pk1(W1[t]);
  }
}

// ---------------- GEMM1: h1 = bf16(x) @ bf16(W1) via MFMA, bf16 out ----------------
// Block: 256 thr = 4 waves; each wave: 32 rows x 128 cols. Whole B in LDS, staged once.

__global__ __launch_bounds__(256) void k_gemm1(const float* __restrict__ x,
                                               const uint4* __restrict__ w1s,
                                               unsigned* __restrict__ h1u) {
  __shared__ char sB[65536];  // swizzled Bt[128][256] bf16
  int tid = threadIdx.x;
  {  // linear 64KB stage: coalesced global read, conflict-free LDS write
    uint4* d = (uint4*)sB;
    for (int i = 0; i < 16; i++) d[tid + i * 256] = w1s[tid + i * 256];
  }
  __syncthreads();

  int lane = tid & 63, wid = tid >> 6;
  int r16 = lane & 15, kgrp = lane >> 4;
  int rowbase = blockIdx.x * 128 + wid * 32;
  int ra0 = min(rowbase + r16, N_NODES - 1);        // A row, m=0 (clamped)
  int ra1 = min(rowbase + 16 + r16, N_NODES - 1);   // A row, m=1

  f32x4 acc[2][8];
#pragma unroll
  for (int m = 0; m < 2; m++)
#pragma unroll
    for (int n = 0; n < 8; n++) acc[m][n] = (f32x4){0.f, 0.f, 0.f, 0.f};

  for (int kt8 = 0; kt8 < 8; kt8++) {
    int k0 = kt8 * 32 + kgrp * 8;  // this lane's 8-elem k-slice
    union { uint4 u; short8 s; } a[2];
#pragma unroll
    for (int m = 0; m < 2; m++) {
      const float* ap = x + (size_t)(m ? ra1 : ra0) * NFEAT + k0;
      float4 v0 = *(const float4*)ap;
      float4 v1 = *(const float4*)(ap + 4);
      a[m].u.x = pk2(v0.x, v0.y);
      a[m].u.y = pk2(v0.z, v0.w);
      a[m].u.z = pk2(v1.x, v1.y);
      a[m].u.w = pk2(v1.z, v1.w);
    }
#pragma unroll
    for (int n = 0; n < 8; n++) {
      int c = 16 * n + r16;
      int off = (c * 512 + k0 * 2) ^ ((c & 7) << 4);
      short8 b = *(const short8*)(sB + off);
      acc[0][n] = __builtin_amdgcn_mfma_f32_16x16x32_bf16(a[0].s, b, acc[0][n], 0, 0, 0);
      acc[1][n] = __builtin_amdgcn_mfma_f32_16x16x32_bf16(a[1].s, b, acc[1][n], 0, 0, 0);
    }
  }

  // epilogue: C/D layout col=lane&15, row=(lane>>4)*4+j; pack col pairs via shfl_xor(1)
#pragma unroll
  for (int m = 0; m < 2; m++) {
    int rb = rowbase + m * 16 + kgrp * 4;
#pragma unroll
    for (int n = 0; n < 8; n++) {
      f32x4 v = acc[m][n];
#pragma unroll
      for (int j = 0; j < 4; j++) {
        float o = __shfl_xor(v[j], 1);
        int row = rb + j;
        if (!(lane & 1) && row < N_NODES)
          h1u[(size_t)row * 64 + 8 * n + (r16 >> 1)] = pk2(v[j], o);
      }
    }
  }
}

// ---------------- SpMM1 + bias + ReLU: one wave per node, bf16 gather, x4 unroll ----------------

__global__ __launch_bounds__(256) void k_spmm1(const unsigned* __restrict__ h1u,
                                               const int* __restrict__ rowptr,
                                               const int2* __restrict__ esw,
                                               const float* __restrict__ bias1,
                                               float* __restrict__ hout) {
  int node = (blockIdx.x * 256 + threadIdx.x) >> 6;
  int lane = threadIdx.x & 63;
  if (node >= N_NODES) return;
  int beg = rowptr[node], end = rowptr[node + 1];
  float a0 = 0.f, a1 = 0.f, b0 = 0.f, b1 = 0.f;
  float c0 = 0.f, c1 = 0.f, d0 = 0.f, d1 = 0.f;
  int j = beg;
  for (; j + 3 < end; j += 4) {
    int2 e0 = esw[j], e1 = esw[j + 1], e2 = esw[j + 2], e3 = esw[j + 3];
    unsigned u0 = h1u[(size_t)e0.x * 64 + lane];
    unsigned u1 = h1u[(size_t)e1.x * 64 + lane];
    unsigned u2 = h1u[(size_t)e2.x * 64 + lane];
    unsigned u3 = h1u[(size_t)e3.x * 64 + lane];
    float w0 = __int_as_float(e0.y), w1 = __int_as_float(e1.y);
    float w2 = __int_as_float(e2.y), w3 = __int_as_float(e3.y);
    a0 = fmaf(w0, blo(u0), a0); a1 = fmaf(w0, bhi(u0), a1);
    b0 = fmaf(w1, blo(u1), b0); b1 = fmaf(w1, bhi(u1), b1);
    c0 = fmaf(w2, blo(u2), c0); c1 = fmaf(w2, bhi(u2), c1);
    d0 = fmaf(w3, blo(u3), d0); d1 = fmaf(w3, bhi(u3), d1);
  }
  for (; j < end; j++) {
    int2 e0 = esw[j];
    unsigned u0 = h1u[(size_t)e0.x * 64 + lane];
    float w0 = __int_as_float(e0.y);
    a0 = fmaf(w0, blo(u0), a0); a1 = fmaf(w0, bhi(u0), a1);
  }
  float r0 = (a0 + b0) + (c0 + d0) + bias1[2 * lane];
  float r1 = (a1 + b1) + (c1 + d1) + bias1[2 * lane + 1];
  float2 o = make_float2(fmaxf(r0, 0.f), fmaxf(r1, 0.f));
  *(float2*)&hout[(size_t)node * NHID + 2 * lane] = o;
}

// ---------------- GEMM2: h2 = h @ W2  (f32 in, bf16 out) ----------------

__global__ __launch_bounds__(256) void k_gemm2(const float* __restrict__ h,
                                               const float* __restrict__ W2,
                                               unsigned short* __restrict__ h2b) {
  __shared__ float hs[32][132];
  __shared__ float w2t[40][132];
  int tid = threadIdx.x;
  int row0 = blockIdx.x * 32;
  for (int i = tid; i < NHID * NCLASS; i += 256) {
    int k = i / NCLASS, c = i % NCLASS;
    w2t[c][k] = W2[i];
  }
  for (int i = tid; i < 1024; i += 256) {
    int r = i >> 5;
    int c4 = (i & 31) << 2;
    *(float4*)&hs[r][c4] = *(const float4*)&h[(size_t)(row0 + r) * NHID + c4];
  }
  __syncthreads();
  int r = tid >> 3;
  int c0 = (tid & 7) * 5;
  float acc[5] = {0, 0, 0, 0, 0};
  for (int k = 0; k < NHID; k += 4) {
    float4 a = *(float4*)&hs[r][k];
#pragma unroll
    for (int j = 0; j < 5; j++) {
      float4 b = *(float4*)&w2t[c0 + j][k];
      acc[j] += a.x * b.x + a.y * b.y + a.z * b.z + a.w * b.w;
    }
  }
#pragma unroll
  for (int j = 0; j < 5; j++) h2b[(size_t)(row0 + r) * NCLASS + c0 + j] = pk1(acc[j]);
}

// ---------------- SpMM2 + bias: wave per node, 3-way edge split, bf16 gather ----------------

__global__ __launch_bounds__(256) void k_spmm2(const unsigned* __restrict__ h2u,
                                               const int* __restrict__ rowptr,
                                               const int2* __restrict__ esw,
                                               const float* __restrict__ b2,
                                               float* __restrict__ out) {
  int node = (blockIdx.x * 256 + threadIdx.x) >> 6;
  int lane = threadIdx.x & 63;
  if (node >= N_NODES) return;
  int beg = rowptr[node], end = rowptr[node + 1];
  int g = lane / 20;       // 0..2 active, 3 = idle tail (lanes 60..63)
  int jj = lane - g * 20;  // 0..19
  float accA = 0.f, accB = 0.f;
  if (g < 3) {
    for (int e = beg + g; e < end; e += 3) {
      int2 p = esw[e];
      unsigned u = h2u[(size_t)p.x * 20 + jj];
      float w = __int_as_float(p.y);
      accA = fmaf(w, blo(u), accA);
      accB = fmaf(w, bhi(u), accB);
    }
  }
  float tA = accA + __shfl(accA, lane + 20) + __shfl(accA, lane + 40);
  float tB = accB + __shfl(accB, lane + 20) + __shfl(accB, lane + 40);
  if (lane < 20) {
    float2 o = make_float2(tA + b2[2 * lane], tB + b2[2 * lane + 1]);
    *(float2*)&out[(size_t)node * NCLASS + 2 * lane] = o;
  }
}

extern "C" void kernel_launch(void* const* d_in, const int* in_sizes, int n_in,
                              void* d_out, int out_size, void* d_ws, size_t ws_size,
                              hipStream_t stream) {
  const float* x = (const float*)d_in[0];
  const int* src_in = (const int*)d_in[1];
  const int* dst_in = (const int*)d_in[2];
  const float* w_in = (const float*)d_in[3];
  const float* W1 = (const float*)d_in[4];
  const float* b1 = (const float*)d_in[5];
  const float* W2 = (const float*)d_in[6];
  const float* b2 = (const float*)d_in[7];
  float* out = (float*)d_out;

  // workspace layout (16B-aligned chunks)
  unsigned short* h1b = (unsigned short*)d_ws;                    // 25.6 MB
  float* hbuf = (float*)(h1b + (size_t)N_NODES * NHID);           // 51.2 MB
  unsigned short* h2b = (unsigned short*)(hbuf + (size_t)N_NODES * NHID);  // 8 MB
  int* rowptr = (int*)(h2b + (size_t)N_NODES * NCLASS);           // 100004 ints
  int* deg = rowptr + 100004;                                     // N (doubles as cursor)
  int* bsums = deg + N_NODES;                                     // 512
  int2* esw = (int2*)(bsums + 512);                               // 12.8 MB
  unsigned short* w1s = (unsigned short*)(esw + N_EDGES);         // 64 KB swizzled bf16 W1^T

  int nbN = (N_NODES + 255) / 256;  // 391
  int nbE = (N_EDGES + 255) / 256;  // 6250

  k_prepw1<<<128, 256, 0, stream>>>(W1, w1s);
  hipMemsetAsync(deg, 0, N_NODES * sizeof(int), stream);
  k_hist<<<nbE, 256, 0, stream>>>(dst_in, deg);
  k_scan1<<<nbN, 256, 0, stream>>>(deg, rowptr, bsums);
  k_scan2<<<1, 512, 0, stream>>>(bsums, nbN);
  k_scan3<<<nbN, 256, 0, stream>>>(rowptr, bsums);
  hipMemsetAsync(deg, 0, N_NODES * sizeof(int), stream);
  k_scatter<<<nbE, 256, 0, stream>>>(src_in, dst_in, w_in, rowptr, deg, esw);

  k_gemm1<<<(N_NODES + 127) / 128, 256, 0, stream>>>(x, (const uint4*)w1s, (unsigned*)h1b);
  k_spmm1<<<(N_NODES + 3) / 4, 256, 0, stream>>>((const unsigned*)h1b, rowptr, esw, b1, hbuf);
  k_gemm2<<<N_NODES / 32, 256, 0, stream>>>(hbuf, W2, h2b);
  k_spmm2<<<(N_NODES + 3) / 4, 256, 0, stream>>>((const unsigned*)h2b, rowptr, esw, b2, out);
}

// Round 4
// 366.438 us; speedup vs baseline: 1.7574x; 1.0341x over previous
//
#include <hip/hip_runtime.h>

#define N_NODES 100000
#define N_EDGES 1600000
#define NFEAT 256
#define NHID 128
#define NCLASS 40

#define NGROUP 8
#define NODES_PER_GROUP 12500  // N_NODES / NGROUP exactly
#define EDGES_PER_BLOCK 2048   // 256 threads x 8
#define NCHUNK ((N_EDGES + EDGES_PER_BLOCK - 1) / EDGES_PER_BLOCK)  // 782

using short8 = __attribute__((ext_vector_type(8))) short;
using f32x4 = __attribute__((ext_vector_type(4))) float;

// ---------- bf16 helpers ----------
__device__ inline float blo(unsigned u) { return __uint_as_float(u << 16); }
__device__ inline float bhi(unsigned u) { return __uint_as_float(u & 0xffff0000u); }
__device__ inline unsigned pk2(float a, float b) {  // 2xf32 -> packed bf16 (RNE)
  unsigned x = __float_as_uint(a), y = __float_as_uint(b);
  unsigned lo = (x + 0x7FFFu + ((x >> 16) & 1u)) >> 16;
  unsigned hi = (y + 0x7FFFu + ((y >> 16) & 1u)) >> 16;
  return lo | (hi << 16);
}
__device__ inline unsigned short pk1(float a) {
  unsigned x = __float_as_uint(a);
  return (unsigned short)((x + 0x7FFFu + ((x >> 16) & 1u)) >> 16);
}

// ---------------- CSR build (XCD-partitioned by dst range) ----------------

__global__ __launch_bounds__(256) void k_hist(const int* __restrict__ dst,
                                              int* __restrict__ deg) {
  int g = blockIdx.x & (NGROUP - 1);
  int chunk = blockIdx.x >> 3;
  int lo = g * NODES_PER_GROUP, hi = lo + NODES_PER_GROUP;
  int base = chunk * EDGES_PER_BLOCK + threadIdx.x;
#pragma unroll
  for (int i = 0; i < 8; i++) {
    int e = base + i * 256;
    if (e < N_EDGES) {
      int d = dst[e];
      if (d >= lo && d < hi) atomicAdd(&deg[d], 1);
    }
  }
}

__global__ void k_scan1(const int* __restrict__ deg, int* __restrict__ rowptr,
                        int* __restrict__ bsums) {
  __shared__ int s[256];
  int t = threadIdx.x;
  int i = blockIdx.x * 256 + t;
  int v = (i < N_NODES) ? deg[i] : 0;
  s[t] = v;
  __syncthreads();
  for (int off = 1; off < 256; off <<= 1) {
    int u = (t >= off) ? s[t - off] : 0;
    __syncthreads();
    s[t] += u;
    __syncthreads();
  }
  if (i < N_NODES) rowptr[i + 1] = s[t];
  if (t == 255) bsums[blockIdx.x] = s[255];
  if (i == 0) rowptr[0] = 0;
}

__global__ void k_scan2(int* __restrict__ bsums, int nb) {
  __shared__ int s[512];
  int t = threadIdx.x;
  int v = (t < nb) ? bsums[t] : 0;
  s[t] = v;
  __syncthreads();
  for (int off = 1; off < 512; off <<= 1) {
    int u = (t >= off) ? s[t - off] : 0;
    __syncthreads();
    s[t] += u;
    __syncthreads();
  }
  if (t < nb) bsums[t] = s[t] - v;  // exclusive
}

__global__ void k_scan3(int* __restrict__ rowptr, const int* __restrict__ bsums) {
  int i = blockIdx.x * 256 + threadIdx.x;
  if (i < N_NODES) rowptr[i + 1] += bsums[blockIdx.x];
}

__global__ __launch_bounds__(256) void k_scatter(const int* __restrict__ src,
                                                 const int* __restrict__ dst,
                                                 const float* __restrict__ w,
                                                 const int* __restrict__ rowptr,
                                                 int* __restrict__ cursor,
                                                 int2* __restrict__ esw) {
  int g = blockIdx.x & (NGROUP - 1);
  int chunk = blockIdx.x >> 3;
  int lo = g * NODES_PER_GROUP, hi = lo + NODES_PER_GROUP;
  int base = chunk * EDGES_PER_BLOCK + threadIdx.x;
#pragma unroll
  for (int i = 0; i < 8; i++) {
    int e = base + i * 256;
    if (e < N_EDGES) {
      int d = dst[e];
      if (d >= lo && d < hi) {
        int pos = rowptr[d] + atomicAdd(&cursor[d], 1);
        esw[pos] = make_int2(src[e], __float_as_int(w[e]));
      }
    }
  }
}

// ---------------- W1 prep: bf16(W1^T) with XOR-swizzle, for linear LDS staging ----------------

__global__ void k_prepw1(const float* __restrict__ W1, unsigned short* __restrict__ w1s) {
  int t = blockIdx.x * 256 + threadIdx.x;
  if (t < NFEAT * NHID) {
    int k = t >> 7, c = t & 127;
    int idx = (c * 256 + k) ^ ((c & 7) << 3);  // u16 index (byte XOR (c&7)<<4)
    w1s[idx] = pk1(W1[t]);
  }
}

// ---------------- GEMM1: h1 = bf16(x) @ bf16(W1) via MFMA, bf16 out ----------------

__global__ __launch_bounds__(256) void k_gemm1(const float* __restrict__ x,
                                               const uint4* __restrict__ w1s,
                                               unsigned* __restrict__ h1u) {
  __shared__ char sB[65536];  // swizzled Bt[128][256] bf16
  int tid = threadIdx.x;
  {
    uint4* d = (uint4*)sB;
    for (int i = 0; i < 16; i++) d[tid + i * 256] = w1s[tid + i * 256];
  }
  __syncthreads();

  int lane = tid & 63, wid = tid >> 6;
  int r16 = lane & 15, kgrp = lane >> 4;
  int rowbase = blockIdx.x * 128 + wid * 32;
  int ra0 = min(rowbase + r16, N_NODES - 1);
  int ra1 = min(rowbase + 16 + r16, N_NODES - 1);

  f32x4 acc[2][8];
#pragma unroll
  for (int m = 0; m < 2; m++)
#pragma unroll
    for (int n = 0; n < 8; n++) acc[m][n] = (f32x4){0.f, 0.f, 0.f, 0.f};

  for (int kt8 = 0; kt8 < 8; kt8++) {
    int k0 = kt8 * 32 + kgrp * 8;
    union { uint4 u; short8 s; } a[2];
#pragma unroll
    for (int m = 0; m < 2; m++) {
      const float* ap = x + (size_t)(m ? ra1 : ra0) * NFEAT + k0;
      float4 v0 = *(const float4*)ap;
      float4 v1 = *(const float4*)(ap + 4);
      a[m].u.x = pk2(v0.x, v0.y);
      a[m].u.y = pk2(v0.z, v0.w);
      a[m].u.z = pk2(v1.x, v1.y);
      a[m].u.w = pk2(v1.z, v1.w);
    }
#pragma unroll
    for (int n = 0; n < 8; n++) {
      int c = 16 * n + r16;
      int off = (c * 512 + k0 * 2) ^ ((c & 7) << 4);
      short8 b = *(const short8*)(sB + off);
      acc[0][n] = __builtin_amdgcn_mfma_f32_16x16x32_bf16(a[0].s, b, acc[0][n], 0, 0, 0);
      acc[1][n] = __builtin_amdgcn_mfma_f32_16x16x32_bf16(a[1].s, b, acc[1][n], 0, 0, 0);
    }
  }

#pragma unroll
  for (int m = 0; m < 2; m++) {
    int rb = rowbase + m * 16 + kgrp * 4;
#pragma unroll
    for (int n = 0; n < 8; n++) {
      f32x4 v = acc[m][n];
#pragma unroll
      for (int j = 0; j < 4; j++) {
        float o = __shfl_xor(v[j], 1);
        int row = rb + j;
        if (!(lane & 1) && row < N_NODES)
          h1u[(size_t)row * 64 + 8 * n + (r16 >> 1)] = pk2(v[j], o);
      }
    }
  }
}

// ---------------- SpMM1 + bias + ReLU: one wave per node, bf16 gather, x4 unroll ----------------

__global__ __launch_bounds__(256) void k_spmm1(const unsigned* __restrict__ h1u,
                                               const int* __restrict__ rowptr,
                                               const int2* __restrict__ esw,
                                               const float* __restrict__ bias1,
                                               float* __restrict__ hout) {
  int node = (blockIdx.x * 256 + threadIdx.x) >> 6;
  int lane = threadIdx.x & 63;
  if (node >= N_NODES) return;
  int beg = rowptr[node], end = rowptr[node + 1];
  float a0 = 0.f, a1 = 0.f, b0 = 0.f, b1 = 0.f;
  float c0 = 0.f, c1 = 0.f, d0 = 0.f, d1 = 0.f;
  int j = beg;
  for (; j + 3 < end; j += 4) {
    int2 e0 = esw[j], e1 = esw[j + 1], e2 = esw[j + 2], e3 = esw[j + 3];
    unsigned u0 = h1u[(size_t)e0.x * 64 + lane];
    unsigned u1 = h1u[(size_t)e1.x * 64 + lane];
    unsigned u2 = h1u[(size_t)e2.x * 64 + lane];
    unsigned u3 = h1u[(size_t)e3.x * 64 + lane];
    float w0 = __int_as_float(e0.y), w1 = __int_as_float(e1.y);
    float w2 = __int_as_float(e2.y), w3 = __int_as_float(e3.y);
    a0 = fmaf(w0, blo(u0), a0); a1 = fmaf(w0, bhi(u0), a1);
    b0 = fmaf(w1, blo(u1), b0); b1 = fmaf(w1, bhi(u1), b1);
    c0 = fmaf(w2, blo(u2), c0); c1 = fmaf(w2, bhi(u2), c1);
    d0 = fmaf(w3, blo(u3), d0); d1 = fmaf(w3, bhi(u3), d1);
  }
  for (; j < end; j++) {
    int2 e0 = esw[j];
    unsigned u0 = h1u[(size_t)e0.x * 64 + lane];
    float w0 = __int_as_float(e0.y);
    a0 = fmaf(w0, blo(u0), a0); a1 = fmaf(w0, bhi(u0), a1);
  }
  float r0 = (a0 + b0) + (c0 + d0) + bias1[2 * lane];
  float r1 = (a1 + b1) + (c1 + d1) + bias1[2 * lane + 1];
  float2 o = make_float2(fmaxf(r0, 0.f), fmaxf(r1, 0.f));
  *(float2*)&hout[(size_t)node * NHID + 2 * lane] = o;
}

// ---------------- GEMM2: h2 = h @ W2  (f32 in, bf16 out) ----------------

__global__ __launch_bounds__(256) void k_gemm2(const float* __restrict__ h,
                                               const float* __restrict__ W2,
                                               unsigned short* __restrict__ h2b) {
  __shared__ float hs[32][132];
  __shared__ float w2t[40][132];
  int tid = threadIdx.x;
  int row0 = blockIdx.x * 32;
  for (int i = tid; i < NHID * NCLASS; i += 256) {
    int k = i / NCLASS, c = i % NCLASS;
    w2t[c][k] = W2[i];
  }
  for (int i = tid; i < 1024; i += 256) {
    int r = i >> 5;
    int c4 = (i & 31) << 2;
    *(float4*)&hs[r][c4] = *(const float4*)&h[(size_t)(row0 + r) * NHID + c4];
  }
  __syncthreads();
  int r = tid >> 3;
  int c0 = (tid & 7) * 5;
  float acc[5] = {0, 0, 0, 0, 0};
  for (int k = 0; k < NHID; k += 4) {
    float4 a = *(float4*)&hs[r][k];
#pragma unroll
    for (int j = 0; j < 5; j++) {
      float4 b = *(float4*)&w2t[c0 + j][k];
      acc[j] += a.x * b.x + a.y * b.y + a.z * b.z + a.w * b.w;
    }
  }
#pragma unroll
  for (int j = 0; j < 5; j++) h2b[(size_t)(row0 + r) * NCLASS + c0 + j] = pk1(acc[j]);
}

// ---------------- SpMM2 + bias: wave per node, 3-way edge split, bf16 gather ----------------

__global__ __launch_bounds__(256) void k_spmm2(const unsigned* __restrict__ h2u,
                                               const int* __restrict__ rowptr,
                                               const int2* __restrict__ esw,
                                               const float* __restrict__ b2,
                                               float* __restrict__ out) {
  int node = (blockIdx.x * 256 + threadIdx.x) >> 6;
  int lane = threadIdx.x & 63;
  if (node >= N_NODES) return;
  int beg = rowptr[node], end = rowptr[node + 1];
  int g = lane / 20;
  int jj = lane - g * 20;
  float accA = 0.f, accB = 0.f;
  if (g < 3) {
    for (int e = beg + g; e < end; e += 3) {
      int2 p = esw[e];
      unsigned u = h2u[(size_t)p.x * 20 + jj];
      float w = __int_as_float(p.y);
      accA = fmaf(w, blo(u), accA);
      accB = fmaf(w, bhi(u), accB);
    }
  }
  float tA = accA + __shfl(accA, lane + 20) + __shfl(accA, lane + 40);
  float tB = accB + __shfl(accB, lane + 20) + __shfl(accB, lane + 40);
  if (lane < 20) {
    float2 o = make_float2(tA + b2[2 * lane], tB + b2[2 * lane + 1]);
    *(float2*)&out[(size_t)node * NCLASS + 2 * lane] = o;
  }
}

extern "C" void kernel_launch(void* const* d_in, const int* in_sizes, int n_in,
                              void* d_out, int out_size, void* d_ws, size_t ws_size,
                              hipStream_t stream) {
  const float* x = (const float*)d_in[0];
  const int* src_in = (const int*)d_in[1];
  const int* dst_in = (const int*)d_in[2];
  const float* w_in = (const float*)d_in[3];
  const float* W1 = (const float*)d_in[4];
  const float* b1 = (const float*)d_in[5];
  const float* W2 = (const float*)d_in[6];
  const float* b2 = (const float*)d_in[7];
  float* out = (float*)d_out;

  // workspace layout (16B-aligned chunks)
  unsigned short* h1b = (unsigned short*)d_ws;                    // 25.6 MB
  float* hbuf = (float*)(h1b + (size_t)N_NODES * NHID);           // 51.2 MB
  unsigned short* h2b = (unsigned short*)(hbuf + (size_t)N_NODES * NHID);  // 8 MB
  int* rowptr = (int*)(h2b + (size_t)N_NODES * NCLASS);           // 100004 ints
  int* deg = rowptr + 100004;                                     // N (doubles as cursor)
  int* bsums = deg + N_NODES;                                     // 512
  int2* esw = (int2*)(bsums + 512);                               // 12.8 MB
  unsigned short* w1s = (unsigned short*)(esw + N_EDGES);         // 64 KB swizzled bf16 W1^T

  int nbN = (N_NODES + 255) / 256;  // 391

  k_prepw1<<<128, 256, 0, stream>>>(W1, w1s);
  hipMemsetAsync(deg, 0, N_NODES * sizeof(int), stream);
  k_hist<<<NCHUNK * NGROUP, 256, 0, stream>>>(dst_in, deg);
  k_scan1<<<nbN, 256, 0, stream>>>(deg, rowptr, bsums);
  k_scan2<<<1, 512, 0, stream>>>(bsums, nbN);
  k_scan3<<<nbN, 256, 0, stream>>>(rowptr, bsums);
  hipMemsetAsync(deg, 0, N_NODES * sizeof(int), stream);
  k_scatter<<<NCHUNK * NGROUP, 256, 0, stream>>>(src_in, dst_in, w_in, rowptr, deg, esw);

  k_gemm1<<<(N_NODES + 127) / 128, 256, 0, stream>>>(x, (const uint4*)w1s, (unsigned*)h1b);
  k_spmm1<<<(N_NODES + 3) / 4, 256, 0, stream>>>((const unsigned*)h1b, rowptr, esw, b1, hbuf);
  k_gemm2<<<N_NODES / 32, 256, 0, stream>>>(hbuf, W2, h2b);
  k_spmm2<<<(N_NODES + 3) / 4, 256, 0, stream>>>((const unsigned*)h2b, rowptr, esw, b2, out);
}